// Round 5
// baseline (836.299 us; speedup 1.0000x reference)
//
#include <hip/hip_runtime.h>
#include <stdint.h>

#define S_LEN 2048
#define HEADS 16
#define DIM   64
// bh = b*HEADS + h, BH = 32.

typedef float  f4v  __attribute__((ext_vector_type(4)));
typedef float  f2v  __attribute__((ext_vector_type(2)));
typedef float  f16v __attribute__((ext_vector_type(16)));
typedef short  s8v  __attribute__((ext_vector_type(8)));
typedef unsigned int   u4v  __attribute__((ext_vector_type(4)));
typedef unsigned short us4v __attribute__((ext_vector_type(4)));

__device__ __forceinline__ unsigned short f2bf(float f) {
  unsigned int u = __float_as_uint(f);
  u += 0x7fffu + ((u >> 16) & 1u);   // round-to-nearest-even
  return (unsigned short)(u >> 16);
}
__device__ __forceinline__ float bf2f(unsigned short h) {
  return __uint_as_float(((unsigned int)h) << 16);
}
__device__ __forceinline__ unsigned int pk2(float e0, float e1) {
  return (unsigned int)f2bf(e0) | ((unsigned int)f2bf(e1) << 16);
}

// ---- prep: K [B,S,H,D] f32 -> fragment-ordered bf16 hi/lo ----
// Khf/Klf flat: [bh][kt][dc][lane][j=8] ; value = K(s=kt*32+(l&31), d=dc*16+(l>>5)*8+j)
__global__ __launch_bounds__(256) void prep_k(const float* __restrict__ K,
                                              unsigned short* __restrict__ Khf,
                                              unsigned short* __restrict__ Klf) {
  int f = blockIdx.x * 256 + threadIdx.x;          // 2048 blocks -> 524288 threads
  int l  = f & 63;
  int dc = (f >> 6) & 3;
  int kt = (f >> 8) & 63;
  int bh = f >> 14;
  int b = bh >> 4, hh = bh & 15;
  int s  = kt * 32 + (l & 31);
  int d0 = dc * 16 + (l >> 5) * 8;
  const float* src = K + (((size_t)(b * S_LEN + s) * HEADS + hh) << 6) + d0;
  f4v va = *(const f4v*)src;
  f4v vb = *(const f4v*)(src + 4);
  us4v ha, hb, la, lb;
#pragma unroll
  for (int i = 0; i < 4; ++i) {
    unsigned short h = f2bf(va[i]);
    ha[i] = h; la[i] = f2bf(va[i] - bf2f(h));
    unsigned short h2 = f2bf(vb[i]);
    hb[i] = h2; lb[i] = f2bf(vb[i] - bf2f(h2));
  }
  size_t o = (size_t)f * 8;
  *(us4v*)(Khf + o) = ha; *(us4v*)(Khf + o + 4) = hb;
  *(us4v*)(Klf + o) = la; *(us4v*)(Klf + o + 4) = lb;
}

// ---- prep: V [B,S,H,D] f32 -> fragment-ordered bf16 via LDS tile ----
// Vf flat: [bh][kt][kc*2+dblk][lane][j=8] ; value = V(s=kt*32+kc*16+(l>>5)*8+j, d=dblk*32+(l&31))
__global__ __launch_bounds__(256) void prep_v(const float* __restrict__ V,
                                              unsigned short* __restrict__ Vf) {
  __shared__ float tile[32 * 68];                  // pitch 68 floats
  int bh = blockIdx.x >> 6;
  int kt = blockIdx.x & 63;
  int b = bh >> 4, hh = bh & 15;
  int t = threadIdx.x;
  {
    int row = t >> 3, c8 = (t & 7) * 8;
    const float* src =
        V + (((size_t)(b * S_LEN + kt * 32 + row) * HEADS + hh) << 6) + c8;
    f4v va = *(const f4v*)src;
    f4v vb = *(const f4v*)(src + 4);
    *(f4v*)(tile + row * 68 + c8) = va;
    *(f4v*)(tile + row * 68 + c8 + 4) = vb;
  }
  __syncthreads();
  int kc = t >> 7, dblk = (t >> 6) & 1, l = t & 63;
  int s0 = kc * 16 + (l >> 5) * 8;
  int col = dblk * 32 + (l & 31);
  us4v w0, w1;
#pragma unroll
  for (int j = 0; j < 4; ++j) {
    w0[j] = f2bf(tile[(s0 + j) * 68 + col]);
    w1[j] = f2bf(tile[(s0 + 4 + j) * 68 + col]);
  }
  size_t o = ((((size_t)bh * 64 + kt) * 4 + kc * 2 + dblk) * 64 + l) * 8;
  *(us4v*)(Vf + o) = w0;
  *(us4v*)(Vf + o + 4) = w1;
}

// ---- main: flash attention, coalesced streams, exact per-row online softmax,
//      lane-local denominator (pl[16]); PARTIAL=1 -> kv-split with combine ----
template <int PARTIAL>
__global__ __launch_bounds__(256, 4) void attn_fwd(
    const float* __restrict__ Q, const float* __restrict__ MASK,
    const float* __restrict__ U, const unsigned short* __restrict__ Khf,
    const unsigned short* __restrict__ Klf, const unsigned short* __restrict__ Vf,
    float* __restrict__ OUT, float* __restrict__ OPART, float* __restrict__ ML) {
  __shared__ short P_lds[4][2048];                 // per-wave 32x64 shorts
  int bid = blockIdx.x;
  int bh, qt, sp;
  if (PARTIAL) {
    int lid = ((bid & 7) << 7) + (bid >> 3);       // 1024 blocks, bijective
    bh = lid >> 5; qt = (lid >> 1) & 15; sp = lid & 1;
  } else {
    int lid = ((bid & 7) << 6) + (bid >> 3);       // 512 blocks
    bh = lid >> 4; qt = lid & 15; sp = 0;
  }
  const int NT = PARTIAL ? (S_LEN / 64) : (S_LEN / 32);
  const int kv_begin = PARTIAL ? sp * (S_LEN / 2) : 0;

  int wv = threadIdx.x >> 6, ln = threadIdx.x & 63;
  int l31 = ln & 31, h5 = ln >> 5;
  int q0 = qt * 128 + wv * 32;
  int b = bh >> 4, hh = bh & 15;
  short* lds = &P_lds[wv][0];

  // Q A-fragments (hi/lo): lane l -> row q0+l31, d = dc*16 + 8*h5 + j
  const float* qrow = Q + (((size_t)(b * S_LEN + q0 + l31) * HEADS + hh) << 6);
  s8v qfh[4], qfl[4];
#pragma unroll
  for (int dc = 0; dc < 4; ++dc) {
    const float* p = qrow + dc * 16 + 8 * h5;
    f4v va = *(const f4v*)p;
    f4v vb = *(const f4v*)(p + 4);
    u4v wh, wl;
#pragma unroll
    for (int t = 0; t < 4; ++t) {
      float x0 = (t < 2) ? va[2 * t] : vb[2 * (t - 2)];
      float x1 = (t < 2) ? va[2 * t + 1] : vb[2 * (t - 2) + 1];
      unsigned short h0 = f2bf(x0), h1 = f2bf(x1);
      wh[t] = (unsigned)h0 | ((unsigned)h1 << 16);
      wl[t] = pk2(x0 - bf2f(h0), x1 - bf2f(h1));
    }
    qfh[dc] = __builtin_bit_cast(s8v, wh);
    qfl[dc] = __builtin_bit_cast(s8v, wl);
  }

  const float* Mp = MASK + ((size_t)bh << 22) + kv_begin;
  const float* Up = U + ((size_t)bh << 22) + kv_begin;
  const int vbase = (q0 + 4 * h5) * S_LEN + l31;
  const unsigned short* kbh = Khf + ((size_t)bh << 17) + ((size_t)kv_begin << 6);
  const unsigned short* kbl = Klf + ((size_t)bh << 17) + ((size_t)kv_begin << 6);
  const unsigned short* vbp = Vf + ((size_t)bh << 17) + ((size_t)kv_begin << 6);
  const int fl8 = ln * 8;

  f16v o0, o1;
#pragma unroll
  for (int i = 0; i < 16; ++i) { o0[i] = 0.f; o1[i] = 0.f; }
  float mrun[16], pl[16];
#pragma unroll
  for (int i = 0; i < 16; ++i) { mrun[i] = -3.0e38f; pl[i] = 0.f; }

  for (int kt = 0; kt < NT; ++kt) {
    int kv0 = kt << 5;
    // K B-fragments (coalesced 1KB loads)
    s8v kfh[4], kfl[4];
#pragma unroll
    for (int dc = 0; dc < 4; ++dc) {
      size_t off = (size_t)((kt * 4 + dc) << 9) + fl8;
      kfh[dc] = *(const s8v*)(kbh + off);
      kfl[dc] = *(const s8v*)(kbl + off);
    }
    // V B-fragments (coalesced 1KB loads)
    s8v vf[2][2];
#pragma unroll
    for (int kc = 0; kc < 2; ++kc)
#pragma unroll
      for (int db = 0; db < 2; ++db)
        vf[kc][db] = *(const s8v*)(vbp + (size_t)((kt * 4 + kc * 2 + db) << 9) + fl8);
    // mask / u in C-layout: reg r -> row q0+8*(r>>2)+4*h5+(r&3), col kv0+l31 (coalesced)
    float mk[16], uk[16];
#pragma unroll
    for (int r = 0; r < 16; ++r) {
      int off = vbase + kv0 + (8 * (r >> 2) + (r & 3)) * S_LEN;
      mk[r] = Mp[off];
      uk[r] = Up[off];
    }
    // S = Q·K^T (fp32-accurate via hi/lo split)
    f16v sc;
#pragma unroll
    for (int i = 0; i < 16; ++i) sc[i] = 0.f;
#pragma unroll
    for (int dc = 0; dc < 4; ++dc) {
      sc = __builtin_amdgcn_mfma_f32_32x32x16_bf16(qfh[dc], kfh[dc], sc, 0, 0, 0);
      sc = __builtin_amdgcn_mfma_f32_32x32x16_bf16(qfl[dc], kfh[dc], sc, 0, 0, 0);
      sc = __builtin_amdgcn_mfma_f32_32x32x16_bf16(qfh[dc], kfl[dc], sc, 0, 0, 0);
    }
    // scores + exact per-row tile max (5-step butterfly within each 32-lane half)
    float sv[16], tmax[16];
#pragma unroll
    for (int r = 0; r < 16; ++r) {
      sv[r] = fmaf(sc[r], 8.0f, mk[r]);
      tmax[r] = sv[r];
    }
#pragma unroll
    for (int d = 1; d < 32; d <<= 1)
#pragma unroll
      for (int r = 0; r < 16; ++r)
        tmax[r] = fmaxf(tmax[r], __shfl_xor(tmax[r], d));
    // defer-max (THR=8), wave-uniform trigger, per-row rescale (all lane-local)
    bool grow = false;
#pragma unroll
    for (int r = 0; r < 16; ++r) grow |= (tmax[r] > mrun[r] + 8.0f);
    if (__any(grow)) {
      float alr[16];
#pragma unroll
      for (int r = 0; r < 16; ++r) {
        float mn = fmaxf(mrun[r], tmax[r]);
        alr[r] = __expf(mrun[r] - mn);
        mrun[r] = mn;
      }
#pragma unroll
      for (int i = 0; i < 16; ++i) { o0[i] *= alr[i]; o1[i] *= alr[i]; pl[i] *= alr[i]; }
    }
    // P' = exp(sv - mrun)/0.9; pl += P' (undropped); store dropped bf16 to LDS [q][k]
#pragma unroll
    for (int r = 0; r < 16; ++r) {
      float pp = __expf(sv[r] - mrun[r]) * (1.0f / 0.9f);
      pl[r] += pp;
      float pd = (uk[r] >= 0.1f) ? pp : 0.f;
      unsigned short bits = f2bf(pd);
      int qr = 8 * (r >> 2) + 4 * h5 + (r & 3);
      lds[qr * 64 + (((l31 >> 3) ^ (qr & 7)) << 3) + (l31 & 7)] = (short)bits;
    }
    __builtin_amdgcn_sched_barrier(0);             // forbid read-before-write reorder
    // read P A-fragments (swizzled): lane -> row l31, k chunk kc*16+h5*8 (no unpack)
    s8v pa[2];
#pragma unroll
    for (int kc = 0; kc < 2; ++kc) {
      int blk = (2 * kc + h5) ^ (l31 & 7);
      pa[kc] = *(const s8v*)(lds + l31 * 64 + blk * 8);
    }
    // O += P·V
    o0 = __builtin_amdgcn_mfma_f32_32x32x16_bf16(pa[0], vf[0][0], o0, 0, 0, 0);
    o0 = __builtin_amdgcn_mfma_f32_32x32x16_bf16(pa[1], vf[1][0], o0, 0, 0, 0);
    o1 = __builtin_amdgcn_mfma_f32_32x32x16_bf16(pa[0], vf[0][1], o1, 0, 0, 0);
    o1 = __builtin_amdgcn_mfma_f32_32x32x16_bf16(pa[1], vf[1][1], o1, 0, 0, 0);
  }

  // row denominators: butterfly-sum pl over the 32 lanes (rows match o0/o1 regs)
#pragma unroll
  for (int d = 1; d < 32; d <<= 1)
#pragma unroll
    for (int r = 0; r < 16; ++r) pl[r] += __shfl_xor(pl[r], d);

  if (PARTIAL) {
    size_t rowbase = (size_t)bh * S_LEN + q0;
#pragma unroll
    for (int r = 0; r < 16; ++r) {
      int qr = 8 * (r >> 2) + 4 * h5 + (r & 3);
      float* p = OPART + (rowbase + qr) * 128 + sp * 64 + l31;
      p[0]  = o0[r];
      p[32] = o1[r];
    }
#pragma unroll
    for (int r = 0; r < 16; ++r) {
      if (l31 == r) {
        int qr = 8 * (r >> 2) + 4 * h5 + (r & 3);
        f2v s; s[0] = mrun[r]; s[1] = pl[r];
        *(f2v*)(ML + (rowbase + qr) * 4 + sp * 2) = s;
      }
    }
  } else {
#pragma unroll
    for (int r = 0; r < 16; ++r) {
      int qr = 8 * (r >> 2) + 4 * h5 + (r & 3);
      float inv = 1.0f / (0.9f * pl[r]);
      float* orow = OUT + (((size_t)bh * S_LEN + q0 + qr) << 6) + l31;
      orow[0]  = o0[r] * inv;
      orow[32] = o1[r] * inv;
    }
  }
}

// ---- combine: merge 2 kv-splits per q row ----
__global__ __launch_bounds__(256) void combine(const float* __restrict__ OPART,
                                               const float* __restrict__ ML,
                                               float* __restrict__ OUT) {
  int gid = blockIdx.x * 256 + threadIdx.x;        // 1M threads
  size_t row = (size_t)(gid >> 4);                 // bh*2048 + q
  int d4 = (gid & 15) * 4;
  f4v mlv = *(const f4v*)(ML + row * 4);
  float m0 = mlv[0], l0 = mlv[1], m1 = mlv[2], l1 = mlv[3];
  float M = fmaxf(m0, m1);
  float w0 = __expf(m0 - M), w1 = __expf(m1 - M);
  float inv = 1.0f / (0.9f * (l0 * w0 + l1 * w1));
  f4v a = *(const f4v*)(OPART + row * 128 + d4);
  f4v bb = *(const f4v*)(OPART + row * 128 + 64 + d4);
  f4v o;
#pragma unroll
  for (int i = 0; i < 4; ++i) o[i] = (a[i] * w0 + bb[i] * w1) * inv;
  *(f4v*)(OUT + row * 64 + d4) = o;
}

extern "C" void kernel_launch(void* const* d_in, const int* in_sizes, int n_in,
                              void* d_out, int out_size, void* d_ws, size_t ws_size,
                              hipStream_t stream) {
  const float* Q = (const float*)d_in[0];
  const float* K = (const float*)d_in[1];
  const float* V = (const float*)d_in[2];
  const float* M = (const float*)d_in[3];
  const float* U = (const float*)d_in[4];
  float* out = (float*)d_out;

  unsigned short* Khf = (unsigned short*)d_ws;              // 8 MB
  unsigned short* Klf = Khf + (size_t)(4u << 20);           // 8 MB
  unsigned short* Vf  = Klf + (size_t)(4u << 20);           // 8 MB
  float* Opart = (float*)(Vf + (size_t)(4u << 20));         // 33.5 MB
  float* ML    = Opart + (size_t)65536 * 128;               // 1 MB
  const size_t need = (size_t)24 * 1024 * 1024 + (size_t)65536 * 132 * 4 + (1u << 20);

  prep_k<<<2048, 256, 0, stream>>>(K, Khf, Klf);
  prep_v<<<2048, 256, 0, stream>>>(V, Vf);
  if (ws_size >= need) {
    attn_fwd<1><<<1024, 256, 0, stream>>>(Q, M, U, Khf, Klf, Vf, out, Opart, ML);
    combine<<<4096, 256, 0, stream>>>(Opart, ML, out);
  } else {
    attn_fwd<0><<<512, 256, 0, stream>>>(Q, M, U, Khf, Klf, Vf, out, Opart, ML);
  }
}

// Round 6
// 285.766 us; speedup vs baseline: 2.9265x; 2.9265x over previous
//
#include <hip/hip_runtime.h>
#include <stdint.h>

#define S_LEN 2048
#define HEADS 16
#define DIM   64
// bh = b*HEADS + h, BH = 32.

typedef float  f4v  __attribute__((ext_vector_type(4)));
typedef float  f2v  __attribute__((ext_vector_type(2)));
typedef float  f16v __attribute__((ext_vector_type(16)));
typedef short  s8v  __attribute__((ext_vector_type(8)));
typedef unsigned int   u4v  __attribute__((ext_vector_type(4)));
typedef unsigned short us4v __attribute__((ext_vector_type(4)));

__device__ __forceinline__ unsigned short f2bf(float f) {
  unsigned int u = __float_as_uint(f);
  u += 0x7fffu + ((u >> 16) & 1u);   // round-to-nearest-even
  return (unsigned short)(u >> 16);
}
__device__ __forceinline__ float bf2f(unsigned short h) {
  return __uint_as_float(((unsigned int)h) << 16);
}
__device__ __forceinline__ unsigned int pk2(float e0, float e1) {
  return (unsigned int)f2bf(e0) | ((unsigned int)f2bf(e1) << 16);
}

// ---- prep: K [B,S,H,D] f32 -> fragment-ordered bf16 hi/lo ----
// Khf/Klf flat: [bh][kt][dc][lane][j=8] ; value = K(s=kt*32+(l&31), d=dc*16+(l>>5)*8+j)
__global__ __launch_bounds__(256) void prep_k(const float* __restrict__ K,
                                              unsigned short* __restrict__ Khf,
                                              unsigned short* __restrict__ Klf) {
  int f = blockIdx.x * 256 + threadIdx.x;          // 2048 blocks -> 524288 threads
  int l  = f & 63;
  int dc = (f >> 6) & 3;
  int kt = (f >> 8) & 63;
  int bh = f >> 14;
  int b = bh >> 4, hh = bh & 15;
  int s  = kt * 32 + (l & 31);
  int d0 = dc * 16 + (l >> 5) * 8;
  const float* src = K + (((size_t)(b * S_LEN + s) * HEADS + hh) << 6) + d0;
  f4v va = *(const f4v*)src;
  f4v vb = *(const f4v*)(src + 4);
  us4v ha, hb, la, lb;
#pragma unroll
  for (int i = 0; i < 4; ++i) {
    unsigned short h = f2bf(va[i]);
    ha[i] = h; la[i] = f2bf(va[i] - bf2f(h));
    unsigned short h2 = f2bf(vb[i]);
    hb[i] = h2; lb[i] = f2bf(vb[i] - bf2f(h2));
  }
  size_t o = (size_t)f * 8;
  *(us4v*)(Khf + o) = ha; *(us4v*)(Khf + o + 4) = hb;
  *(us4v*)(Klf + o) = la; *(us4v*)(Klf + o + 4) = lb;
}

// ---- prep: V [B,S,H,D] f32 -> fragment-ordered bf16 via LDS tile ----
// Vf flat: [bh][kt][kc*2+dblk][lane][j=8] ; value = V(s=kt*32+kc*16+(l>>5)*8+j, d=dblk*32+(l&31))
__global__ __launch_bounds__(256) void prep_v(const float* __restrict__ V,
                                              unsigned short* __restrict__ Vf) {
  __shared__ float tile[32 * 68];                  // pitch 68 floats
  int bh = blockIdx.x >> 6;
  int kt = blockIdx.x & 63;
  int b = bh >> 4, hh = bh & 15;
  int t = threadIdx.x;
  {
    int row = t >> 3, c8 = (t & 7) * 8;
    const float* src =
        V + (((size_t)(b * S_LEN + kt * 32 + row) * HEADS + hh) << 6) + c8;
    f4v va = *(const f4v*)src;
    f4v vb = *(const f4v*)(src + 4);
    *(f4v*)(tile + row * 68 + c8) = va;
    *(f4v*)(tile + row * 68 + c8 + 4) = vb;
  }
  __syncthreads();
  int kc = t >> 7, dblk = (t >> 6) & 1, l = t & 63;
  int s0 = kc * 16 + (l >> 5) * 8;
  int col = dblk * 32 + (l & 31);
  us4v w0, w1;
#pragma unroll
  for (int j = 0; j < 4; ++j) {
    w0[j] = f2bf(tile[(s0 + j) * 68 + col]);
    w1[j] = f2bf(tile[(s0 + 4 + j) * 68 + col]);
  }
  size_t o = ((((size_t)bh * 64 + kt) * 4 + kc * 2 + dblk) * 64 + l) * 8;
  *(us4v*)(Vf + o) = w0;
  *(us4v*)(Vf + o + 4) = w1;
}

// ---- main: flash attention, coalesced streams, exact per-row online softmax,
//      lane-local denominator (pl[16]); PARTIAL=1 -> kv-split with combine ----
// NOTE: launch_bounds min-waves MUST stay 2 — (256,4) forces a 64-VGPR fit and
// the compiler spills ~2.7 GB/pass to scratch (round-5 regression).
template <int PARTIAL>
__global__ __launch_bounds__(256, 2) void attn_fwd(
    const float* __restrict__ Q, const float* __restrict__ MASK,
    const float* __restrict__ U, const unsigned short* __restrict__ Khf,
    const unsigned short* __restrict__ Klf, const unsigned short* __restrict__ Vf,
    float* __restrict__ OUT, float* __restrict__ OPART, float* __restrict__ ML) {
  __shared__ short P_lds[4][2048];                 // per-wave 32x64 shorts
  int bid = blockIdx.x;
  int bh, qt, sp;
  if (PARTIAL) {
    int lid = ((bid & 7) << 7) + (bid >> 3);       // 1024 blocks, bijective
    bh = lid >> 5; qt = (lid >> 1) & 15; sp = lid & 1;
  } else {
    int lid = ((bid & 7) << 6) + (bid >> 3);       // 512 blocks
    bh = lid >> 4; qt = lid & 15; sp = 0;
  }
  const int NT = PARTIAL ? (S_LEN / 64) : (S_LEN / 32);
  const int kv_begin = PARTIAL ? sp * (S_LEN / 2) : 0;

  int wv = threadIdx.x >> 6, ln = threadIdx.x & 63;
  int l31 = ln & 31, h5 = ln >> 5;
  int q0 = qt * 128 + wv * 32;
  int b = bh >> 4, hh = bh & 15;
  short* lds = &P_lds[wv][0];

  // Q A-fragments (hi/lo): lane l -> row q0+l31, d = dc*16 + 8*h5 + j
  const float* qrow = Q + (((size_t)(b * S_LEN + q0 + l31) * HEADS + hh) << 6);
  s8v qfh[4], qfl[4];
#pragma unroll
  for (int dc = 0; dc < 4; ++dc) {
    const float* p = qrow + dc * 16 + 8 * h5;
    f4v va = *(const f4v*)p;
    f4v vb = *(const f4v*)(p + 4);
    u4v wh, wl;
#pragma unroll
    for (int t = 0; t < 4; ++t) {
      float x0 = (t < 2) ? va[2 * t] : vb[2 * (t - 2)];
      float x1 = (t < 2) ? va[2 * t + 1] : vb[2 * (t - 2) + 1];
      unsigned short h0 = f2bf(x0), h1 = f2bf(x1);
      wh[t] = (unsigned)h0 | ((unsigned)h1 << 16);
      wl[t] = pk2(x0 - bf2f(h0), x1 - bf2f(h1));
    }
    qfh[dc] = __builtin_bit_cast(s8v, wh);
    qfl[dc] = __builtin_bit_cast(s8v, wl);
  }

  const float* Mp = MASK + ((size_t)bh << 22) + kv_begin;
  const float* Up = U + ((size_t)bh << 22) + kv_begin;
  const int vbase = (q0 + 4 * h5) * S_LEN + l31;
  const unsigned short* kbh = Khf + ((size_t)bh << 17) + ((size_t)kv_begin << 6);
  const unsigned short* kbl = Klf + ((size_t)bh << 17) + ((size_t)kv_begin << 6);
  const unsigned short* vbp = Vf + ((size_t)bh << 17) + ((size_t)kv_begin << 6);
  const int fl8 = ln * 8;

  f16v o0, o1;
#pragma unroll
  for (int i = 0; i < 16; ++i) { o0[i] = 0.f; o1[i] = 0.f; }
  float mrun[16], pl[16];
#pragma unroll
  for (int i = 0; i < 16; ++i) { mrun[i] = -3.0e38f; pl[i] = 0.f; }

  for (int kt = 0; kt < NT; ++kt) {
    int kv0 = kt << 5;
    // K B-fragments (coalesced 1KB loads)
    s8v kfh[4], kfl[4];
#pragma unroll
    for (int dc = 0; dc < 4; ++dc) {
      size_t off = (size_t)((kt * 4 + dc) << 9) + fl8;
      kfh[dc] = *(const s8v*)(kbh + off);
      kfl[dc] = *(const s8v*)(kbl + off);
    }
    // V B-fragments (coalesced 1KB loads)
    s8v vf[2][2];
#pragma unroll
    for (int kc = 0; kc < 2; ++kc)
#pragma unroll
      for (int db = 0; db < 2; ++db)
        vf[kc][db] = *(const s8v*)(vbp + (size_t)((kt * 4 + kc * 2 + db) << 9) + fl8);
    // mask in C-layout: reg r -> row q0+8*(r>>2)+4*h5+(r&3), col kv0+l31 (coalesced)
    float mk[16];
#pragma unroll
    for (int r = 0; r < 16; ++r)
      mk[r] = Mp[vbase + kv0 + (8 * (r >> 2) + (r & 3)) * S_LEN];
    // S = Q·K^T (fp32-accurate via hi/lo split)
    f16v sc;
#pragma unroll
    for (int i = 0; i < 16; ++i) sc[i] = 0.f;
#pragma unroll
    for (int dc = 0; dc < 4; ++dc) {
      sc = __builtin_amdgcn_mfma_f32_32x32x16_bf16(qfh[dc], kfh[dc], sc, 0, 0, 0);
      sc = __builtin_amdgcn_mfma_f32_32x32x16_bf16(qfl[dc], kfh[dc], sc, 0, 0, 0);
      sc = __builtin_amdgcn_mfma_f32_32x32x16_bf16(qfh[dc], kfl[dc], sc, 0, 0, 0);
    }
    // dropout-u loads issued here (shorter live range than preloading)
    float uk[16];
#pragma unroll
    for (int r = 0; r < 16; ++r)
      uk[r] = Up[vbase + kv0 + (8 * (r >> 2) + (r & 3)) * S_LEN];
    // scores + exact per-row tile max (5-step butterfly within each 32-lane half)
    float sv[16], tmax[16];
#pragma unroll
    for (int r = 0; r < 16; ++r) {
      sv[r] = fmaf(sc[r], 8.0f, mk[r]);
      tmax[r] = sv[r];
    }
#pragma unroll
    for (int d = 1; d < 32; d <<= 1)
#pragma unroll
      for (int r = 0; r < 16; ++r)
        tmax[r] = fmaxf(tmax[r], __shfl_xor(tmax[r], d));
    // defer-max (THR=8), wave-uniform trigger, per-row rescale (all lane-local)
    bool grow = false;
#pragma unroll
    for (int r = 0; r < 16; ++r) grow |= (tmax[r] > mrun[r] + 8.0f);
    if (__any(grow)) {
      float alr[16];
#pragma unroll
      for (int r = 0; r < 16; ++r) {
        float mn = fmaxf(mrun[r], tmax[r]);
        alr[r] = __expf(mrun[r] - mn);
        mrun[r] = mn;
      }
#pragma unroll
      for (int i = 0; i < 16; ++i) { o0[i] *= alr[i]; o1[i] *= alr[i]; pl[i] *= alr[i]; }
    }
    // P' = exp(sv - mrun)/0.9; pl += P' (undropped); store dropped bf16 to LDS [q][k]
#pragma unroll
    for (int r = 0; r < 16; ++r) {
      float pp = __expf(sv[r] - mrun[r]) * (1.0f / 0.9f);
      pl[r] += pp;
      float pd = (uk[r] >= 0.1f) ? pp : 0.f;
      unsigned short bits = f2bf(pd);
      int qr = 8 * (r >> 2) + 4 * h5 + (r & 3);
      lds[qr * 64 + (((l31 >> 3) ^ (qr & 7)) << 3) + (l31 & 7)] = (short)bits;
    }
    __builtin_amdgcn_sched_barrier(0);             // forbid read-before-write reorder
    // read P A-fragments (swizzled): lane -> row l31, k chunk kc*16+h5*8 (no unpack)
    s8v pa[2];
#pragma unroll
    for (int kc = 0; kc < 2; ++kc) {
      int blk = (2 * kc + h5) ^ (l31 & 7);
      pa[kc] = *(const s8v*)(lds + l31 * 64 + blk * 8);
    }
    // O += P·V
    o0 = __builtin_amdgcn_mfma_f32_32x32x16_bf16(pa[0], vf[0][0], o0, 0, 0, 0);
    o0 = __builtin_amdgcn_mfma_f32_32x32x16_bf16(pa[1], vf[1][0], o0, 0, 0, 0);
    o1 = __builtin_amdgcn_mfma_f32_32x32x16_bf16(pa[0], vf[0][1], o1, 0, 0, 0);
    o1 = __builtin_amdgcn_mfma_f32_32x32x16_bf16(pa[1], vf[1][1], o1, 0, 0, 0);
  }

  // row denominators: butterfly-sum pl over the 32 lanes (rows match o0/o1 regs)
#pragma unroll
  for (int d = 1; d < 32; d <<= 1)
#pragma unroll
    for (int r = 0; r < 16; ++r) pl[r] += __shfl_xor(pl[r], d);

  if (PARTIAL) {
    size_t rowbase = (size_t)bh * S_LEN + q0;
#pragma unroll
    for (int r = 0; r < 16; ++r) {
      int qr = 8 * (r >> 2) + 4 * h5 + (r & 3);
      float* p = OPART + (rowbase + qr) * 128 + sp * 64 + l31;
      p[0]  = o0[r];
      p[32] = o1[r];
    }
#pragma unroll
    for (int r = 0; r < 16; ++r) {
      if (l31 == r) {
        int qr = 8 * (r >> 2) + 4 * h5 + (r & 3);
        f2v s; s[0] = mrun[r]; s[1] = pl[r];
        *(f2v*)(ML + (rowbase + qr) * 4 + sp * 2) = s;
      }
    }
  } else {
#pragma unroll
    for (int r = 0; r < 16; ++r) {
      int qr = 8 * (r >> 2) + 4 * h5 + (r & 3);
      float inv = 1.0f / (0.9f * pl[r]);
      float* orow = OUT + (((size_t)bh * S_LEN + q0 + qr) << 6) + l31;
      orow[0]  = o0[r] * inv;
      orow[32] = o1[r] * inv;
    }
  }
}

// ---- combine: merge 2 kv-splits per q row ----
__global__ __launch_bounds__(256) void combine(const float* __restrict__ OPART,
                                               const float* __restrict__ ML,
                                               float* __restrict__ OUT) {
  int gid = blockIdx.x * 256 + threadIdx.x;        // 1M threads
  size_t row = (size_t)(gid >> 4);                 // bh*2048 + q
  int d4 = (gid & 15) * 4;
  f4v mlv = *(const f4v*)(ML + row * 4);
  float m0 = mlv[0], l0 = mlv[1], m1 = mlv[2], l1 = mlv[3];
  float M = fmaxf(m0, m1);
  float w0 = __expf(m0 - M), w1 = __expf(m1 - M);
  float inv = 1.0f / (0.9f * (l0 * w0 + l1 * w1));
  f4v a = *(const f4v*)(OPART + row * 128 + d4);
  f4v bb = *(const f4v*)(OPART + row * 128 + 64 + d4);
  f4v o;
#pragma unroll
  for (int i = 0; i < 4; ++i) o[i] = (a[i] * w0 + bb[i] * w1) * inv;
  *(f4v*)(OUT + row * 64 + d4) = o;
}

extern "C" void kernel_launch(void* const* d_in, const int* in_sizes, int n_in,
                              void* d_out, int out_size, void* d_ws, size_t ws_size,
                              hipStream_t stream) {
  const float* Q = (const float*)d_in[0];
  const float* K = (const float*)d_in[1];
  const float* V = (const float*)d_in[2];
  const float* M = (const float*)d_in[3];
  const float* U = (const float*)d_in[4];
  float* out = (float*)d_out;

  unsigned short* Khf = (unsigned short*)d_ws;              // 8 MB
  unsigned short* Klf = Khf + (size_t)(4u << 20);           // 8 MB
  unsigned short* Vf  = Klf + (size_t)(4u << 20);           // 8 MB
  float* Opart = (float*)(Vf + (size_t)(4u << 20));         // 33.5 MB
  float* ML    = Opart + (size_t)65536 * 128;               // 1 MB
  const size_t need = (size_t)24 * 1024 * 1024 + (size_t)65536 * 132 * 4 + (1u << 20);

  prep_k<<<2048, 256, 0, stream>>>(K, Khf, Klf);
  prep_v<<<2048, 256, 0, stream>>>(V, Vf);
  if (ws_size >= need) {
    attn_fwd<1><<<1024, 256, 0, stream>>>(Q, M, U, Khf, Klf, Vf, out, Opart, ML);
    combine<<<4096, 256, 0, stream>>>(Opart, ML, out);
  } else {
    attn_fwd<0><<<512, 256, 0, stream>>>(Q, M, U, Khf, Klf, Vf, out, Opart, ML);
  }
}

// Round 7
// 270.671 us; speedup vs baseline: 3.0897x; 1.0558x over previous
//
#include <hip/hip_runtime.h>
#include <stdint.h>

#define S_LEN 2048
#define HEADS 16
#define DIM   64
// bh = b*HEADS + h, BH = 32.

typedef float  f4v  __attribute__((ext_vector_type(4)));
typedef float  f2v  __attribute__((ext_vector_type(2)));
typedef float  f16v __attribute__((ext_vector_type(16)));
typedef short  s8v  __attribute__((ext_vector_type(8)));
typedef unsigned int   u4v  __attribute__((ext_vector_type(4)));
typedef unsigned short us4v __attribute__((ext_vector_type(4)));

#define LOGC 0.105360516f   // ln(1/0.9): folds the 1/(1-p) dropout scale into exp

__device__ __forceinline__ unsigned short f2bf(float f) {
  unsigned int u = __float_as_uint(f);
  u += 0x7fffu + ((u >> 16) & 1u);   // round-to-nearest-even
  return (unsigned short)(u >> 16);
}
__device__ __forceinline__ float bf2f(unsigned short h) {
  return __uint_as_float(((unsigned int)h) << 16);
}
__device__ __forceinline__ unsigned int pk2(float e0, float e1) {
  return (unsigned int)f2bf(e0) | ((unsigned int)f2bf(e1) << 16);
}

// ---- prep: K [B,S,H,D] f32 -> fragment-ordered bf16 hi/lo ----
// Khf/Klf flat: [bh][kt][dc][lane][j=8] ; value = K(s=kt*32+(l&31), d=dc*16+(l>>5)*8+j)
__global__ __launch_bounds__(256) void prep_k(const float* __restrict__ K,
                                              unsigned short* __restrict__ Khf,
                                              unsigned short* __restrict__ Klf) {
  int f = blockIdx.x * 256 + threadIdx.x;          // 2048 blocks -> 524288 threads
  int l  = f & 63;
  int dc = (f >> 6) & 3;
  int kt = (f >> 8) & 63;
  int bh = f >> 14;
  int b = bh >> 4, hh = bh & 15;
  int s  = kt * 32 + (l & 31);
  int d0 = dc * 16 + (l >> 5) * 8;
  const float* src = K + (((size_t)(b * S_LEN + s) * HEADS + hh) << 6) + d0;
  f4v va = *(const f4v*)src;
  f4v vb = *(const f4v*)(src + 4);
  us4v ha, hb, la, lb;
#pragma unroll
  for (int i = 0; i < 4; ++i) {
    unsigned short h = f2bf(va[i]);
    ha[i] = h; la[i] = f2bf(va[i] - bf2f(h));
    unsigned short h2 = f2bf(vb[i]);
    hb[i] = h2; lb[i] = f2bf(vb[i] - bf2f(h2));
  }
  size_t o = (size_t)f * 8;
  *(us4v*)(Khf + o) = ha; *(us4v*)(Khf + o + 4) = hb;
  *(us4v*)(Klf + o) = la; *(us4v*)(Klf + o + 4) = lb;
}

// ---- prep: V [B,S,H,D] f32 -> fragment-ordered bf16 via LDS tile ----
// Vf flat: [bh][kt][kc*2+dblk][lane][j=8] ; value = V(s=kt*32+kc*16+(l>>5)*8+j, d=dblk*32+(l&31))
__global__ __launch_bounds__(256) void prep_v(const float* __restrict__ V,
                                              unsigned short* __restrict__ Vf) {
  __shared__ float tile[32 * 68];                  // pitch 68 floats
  int bh = blockIdx.x >> 6;
  int kt = blockIdx.x & 63;
  int b = bh >> 4, hh = bh & 15;
  int t = threadIdx.x;
  {
    int row = t >> 3, c8 = (t & 7) * 8;
    const float* src =
        V + (((size_t)(b * S_LEN + kt * 32 + row) * HEADS + hh) << 6) + c8;
    f4v va = *(const f4v*)src;
    f4v vb = *(const f4v*)(src + 4);
    *(f4v*)(tile + row * 68 + c8) = va;
    *(f4v*)(tile + row * 68 + c8 + 4) = vb;
  }
  __syncthreads();
  int kc = t >> 7, dblk = (t >> 6) & 1, l = t & 63;
  int s0 = kc * 16 + (l >> 5) * 8;
  int col = dblk * 32 + (l & 31);
  us4v w0, w1;
#pragma unroll
  for (int j = 0; j < 4; ++j) {
    w0[j] = f2bf(tile[(s0 + j) * 68 + col]);
    w1[j] = f2bf(tile[(s0 + 4 + j) * 68 + col]);
  }
  size_t o = ((((size_t)bh * 64 + kt) * 4 + kc * 2 + dblk) * 64 + l) * 8;
  *(us4v*)(Vf + o) = w0;
  *(us4v*)(Vf + o + 4) = w1;
}

// ---- main: flash attention. QK in C-layout (coalesced mask/u), then f32
// scores transposed through wave-private LDS (drop-flag in mantissa LSB);
// softmax fully lane-local in the transposed domain (mrun/pl scalars).
// NOTE: launch_bounds min-waves MUST stay 2 — (256,4) forces a 64-VGPR fit and
// the compiler spills ~2.7 GB/pass to scratch (round-5 regression).
template <int PARTIAL>
__global__ __launch_bounds__(256, 2) void attn_fwd(
    const float* __restrict__ Q, const float* __restrict__ MASK,
    const float* __restrict__ U, const unsigned short* __restrict__ Khf,
    const unsigned short* __restrict__ Klf, const unsigned short* __restrict__ Vf,
    float* __restrict__ OUT, float* __restrict__ OPART, float* __restrict__ ML) {
  __shared__ float S_lds[4][1024];                 // per-wave 32x32 f32 scores
  int bid = blockIdx.x;
  int bh, qt, sp;
  if (PARTIAL) {
    int lid = ((bid & 7) << 7) + (bid >> 3);       // 1024 blocks, bijective
    bh = lid >> 5; qt = (lid >> 1) & 15; sp = lid & 1;
  } else {
    int lid = ((bid & 7) << 6) + (bid >> 3);       // 512 blocks
    bh = lid >> 4; qt = lid & 15; sp = 0;
  }
  const int NT = PARTIAL ? (S_LEN / 64) : (S_LEN / 32);
  const int kv_begin = PARTIAL ? sp * (S_LEN / 2) : 0;

  int wv = threadIdx.x >> 6, ln = threadIdx.x & 63;
  int l31 = ln & 31, h5 = ln >> 5;
  int q0 = qt * 128 + wv * 32;
  int b = bh >> 4, hh = bh & 15;
  float* lds = &S_lds[wv][0];

  // Q A-fragments (hi/lo): lane l -> row q0+l31, d = dc*16 + 8*h5 + j
  const float* qrow = Q + (((size_t)(b * S_LEN + q0 + l31) * HEADS + hh) << 6);
  s8v qfh[4], qfl[4];
#pragma unroll
  for (int dc = 0; dc < 4; ++dc) {
    const float* p = qrow + dc * 16 + 8 * h5;
    f4v va = *(const f4v*)p;
    f4v vb = *(const f4v*)(p + 4);
    u4v wh, wl;
#pragma unroll
    for (int t = 0; t < 4; ++t) {
      float x0 = (t < 2) ? va[2 * t] : vb[2 * (t - 2)];
      float x1 = (t < 2) ? va[2 * t + 1] : vb[2 * (t - 2) + 1];
      unsigned short h0 = f2bf(x0), h1 = f2bf(x1);
      wh[t] = (unsigned)h0 | ((unsigned)h1 << 16);
      wl[t] = pk2(x0 - bf2f(h0), x1 - bf2f(h1));
    }
    qfh[dc] = __builtin_bit_cast(s8v, wh);
    qfl[dc] = __builtin_bit_cast(s8v, wl);
  }

  // mask/u: persistent per-row byte-offset table (saddr + 32-bit voffset form)
  const char* Mp8 = (const char*)(MASK + ((size_t)bh << 22));
  const char* Up8 = (const char*)(U + ((size_t)bh << 22));
  unsigned voff[16];
#pragma unroll
  for (int r = 0; r < 16; ++r)
    voff[r] = (unsigned)((((q0 + 8 * (r >> 2) + 4 * h5 + (r & 3)) * S_LEN) +
                          kv_begin + l31) * 4);

  const unsigned short* kbh = Khf + ((size_t)bh << 17) + ((size_t)kv_begin << 6);
  const unsigned short* kbl = Klf + ((size_t)bh << 17) + ((size_t)kv_begin << 6);
  const unsigned short* vbp = Vf + ((size_t)bh << 17) + ((size_t)kv_begin << 6);
  const int fl8 = ln * 8;

  f16v o0, o1;
#pragma unroll
  for (int i = 0; i < 16; ++i) { o0[i] = 0.f; o1[i] = 0.f; }
  float mrs = -3.0e38f;   // running row max, pre-shifted by -LOGC (lane = row l31)
  float pl  = 0.f;        // undropped sum of P/0.9 for this lane's k-half

  for (int kt = 0; kt < NT; ++kt) {
    // K B-fragments (coalesced 1KB loads)
    s8v kfh[4], kfl[4];
#pragma unroll
    for (int dc = 0; dc < 4; ++dc) {
      size_t off = (size_t)((kt * 4 + dc) << 9) + fl8;
      kfh[dc] = *(const s8v*)(kbh + off);
      kfl[dc] = *(const s8v*)(kbl + off);
    }
    // V B-fragments (coalesced 1KB loads)
    s8v vf[2][2];
#pragma unroll
    for (int kc = 0; kc < 2; ++kc)
#pragma unroll
      for (int db = 0; db < 2; ++db)
        vf[kc][db] = *(const s8v*)(vbp + (size_t)((kt * 4 + kc * 2 + db) << 9) + fl8);
    // mask / u in C-layout (coalesced dword loads via offset table)
    float mk[16], uk[16];
#pragma unroll
    for (int r = 0; r < 16; ++r) {
      mk[r] = *(const float*)(Mp8 + voff[r]);
      uk[r] = *(const float*)(Up8 + voff[r]);
      voff[r] += 128;
    }
    // S = Q·K^T (fp32-accurate via hi/lo split)
    f16v sc;
#pragma unroll
    for (int i = 0; i < 16; ++i) sc[i] = 0.f;
#pragma unroll
    for (int dc = 0; dc < 4; ++dc) {
      sc = __builtin_amdgcn_mfma_f32_32x32x16_bf16(qfh[dc], kfh[dc], sc, 0, 0, 0);
      sc = __builtin_amdgcn_mfma_f32_32x32x16_bf16(qfl[dc], kfh[dc], sc, 0, 0, 0);
      sc = __builtin_amdgcn_mfma_f32_32x32x16_bf16(qfh[dc], kfl[dc], sc, 0, 0, 0);
    }
    // phase A: sv = 8*sc + mask, drop-flag -> mantissa LSB, write f32 [q][k]
    // swizzled: word = qr*32 + ((l31>>2 ^ qr&7)<<2 | l31&3)   (2-way on write)
#pragma unroll
    for (int r = 0; r < 16; ++r) {
      float sv = fmaf(sc[r], 8.0f, mk[r]);
      unsigned bits = (__float_as_uint(sv) & ~1u) | (uk[r] < 0.1f ? 1u : 0u);
      int qr = 8 * (r >> 2) + 4 * h5 + (r & 3);
      lds[qr * 32 + (((((l31 >> 2) ^ (qr & 7)) << 2)) | (l31 & 3))] =
          __uint_as_float(bits);
    }
    __builtin_amdgcn_sched_barrier(0);             // keep reads after writes
    // phase B: transposed read — lane owns row l31; h5 picks k-chunks
    // chunk c covers k=4c..4c+3; this lane needs c in {2h5,2h5+1,4+2h5,5+2h5}
    f4v sq[4];
#pragma unroll
    for (int cc = 0; cc < 4; ++cc) {
      int c = (cc >> 1) * 4 + (cc & 1) + 2 * h5;
      sq[cc] = *(const f4v*)(lds + l31 * 32 + ((c ^ (l31 & 7)) << 2));
    }
    // lane-local row max (15 fmax) + pair across k-halves (1 shfl)
    float tm = -3.0e38f;
#pragma unroll
    for (int cc = 0; cc < 4; ++cc)
#pragma unroll
      for (int w = 0; w < 4; ++w) tm = fmaxf(tm, sq[cc][w]);
    float tmax = fmaxf(tm, __shfl_xor(tm, 32));
    // defer-max (THR=8), wave-uniform trigger
    if (__any(tmax > mrs + (8.0f + LOGC))) {
      float mold = mrs + LOGC;
      float mn = fmaxf(mold, tmax);
      float al = __expf(mold - mn);
      mrs = mn - LOGC;
      pl *= al;
#pragma unroll
      for (int r = 0; r < 16; ++r) {
        float arow = __shfl(al, 8 * (r >> 2) + 4 * h5 + (r & 3));
        o0[r] *= arow; o1[r] *= arow;
      }
    }
    // P' = exp(sv - mrs) = e^{sv-mrun}/0.9 ; pl += P' (undropped); drop -> pack
    u4v pa0, pa1;
#pragma unroll
    for (int cc = 0; cc < 4; ++cc) {
      float p0 = __expf(sq[cc][0] - mrs), p1 = __expf(sq[cc][1] - mrs);
      float p2 = __expf(sq[cc][2] - mrs), p3 = __expf(sq[cc][3] - mrs);
      pl += (p0 + p1) + (p2 + p3);
      float d0 = (__float_as_uint(sq[cc][0]) & 1u) ? 0.f : p0;
      float d1 = (__float_as_uint(sq[cc][1]) & 1u) ? 0.f : p1;
      float d2 = (__float_as_uint(sq[cc][2]) & 1u) ? 0.f : p2;
      float d3 = (__float_as_uint(sq[cc][3]) & 1u) ? 0.f : p3;
      unsigned w0 = pk2(d0, d1), w1 = pk2(d2, d3);
      if (cc < 2) { pa0[2 * cc] = w0; pa0[2 * cc + 1] = w1; }
      else        { pa1[2 * (cc - 2)] = w0; pa1[2 * (cc - 2) + 1] = w1; }
    }
    s8v pa[2] = {__builtin_bit_cast(s8v, pa0), __builtin_bit_cast(s8v, pa1)};
    // O += P·V
    o0 = __builtin_amdgcn_mfma_f32_32x32x16_bf16(pa[0], vf[0][0], o0, 0, 0, 0);
    o0 = __builtin_amdgcn_mfma_f32_32x32x16_bf16(pa[1], vf[1][0], o0, 0, 0, 0);
    o1 = __builtin_amdgcn_mfma_f32_32x32x16_bf16(pa[0], vf[0][1], o1, 0, 0, 0);
    o1 = __builtin_amdgcn_mfma_f32_32x32x16_bf16(pa[1], vf[1][1], o1, 0, 0, 0);
  }

  // combine k-halves of the row sum (lanes R and R+32 hold the two halves)
  pl += __shfl_xor(pl, 32);

  if (PARTIAL) {
    size_t rowbase = (size_t)bh * S_LEN + q0;
#pragma unroll
    for (int r = 0; r < 16; ++r) {
      int qr = 8 * (r >> 2) + 4 * h5 + (r & 3);
      float* p = OPART + (rowbase + qr) * 128 + sp * 64 + l31;
      p[0]  = o0[r];
      p[32] = o1[r];
    }
    if (h5 == 0) {                                  // lane l31 owns row l31
      f2v s; s[0] = mrs; s[1] = pl;
      *(f2v*)(ML + (rowbase + l31) * 4 + sp * 2) = s;
    }
  } else {
    float inv = 1.0f / (0.9f * pl);
#pragma unroll
    for (int r = 0; r < 16; ++r) {
      int qr = 8 * (r >> 2) + 4 * h5 + (r & 3);
      float invv = __shfl(inv, qr);
      float* orow = OUT + (((size_t)bh * S_LEN + q0 + qr) << 6) + l31;
      orow[0]  = o0[r] * invv;
      orow[32] = o1[r] * invv;
    }
  }
}

// ---- combine: merge 2 kv-splits per q row (m stored pre-shifted; consistent) ----
__global__ __launch_bounds__(256) void combine(const float* __restrict__ OPART,
                                               const float* __restrict__ ML,
                                               float* __restrict__ OUT) {
  int gid = blockIdx.x * 256 + threadIdx.x;        // 1M threads
  size_t row = (size_t)(gid >> 4);                 // bh*2048 + q
  int d4 = (gid & 15) * 4;
  f4v mlv = *(const f4v*)(ML + row * 4);
  float m0 = mlv[0], l0 = mlv[1], m1 = mlv[2], l1 = mlv[3];
  float M = fmaxf(m0, m1);
  float w0 = __expf(m0 - M), w1 = __expf(m1 - M);
  float inv = 1.0f / (0.9f * (l0 * w0 + l1 * w1));
  f4v a = *(const f4v*)(OPART + row * 128 + d4);
  f4v bb = *(const f4v*)(OPART + row * 128 + 64 + d4);
  f4v o;
#pragma unroll
  for (int i = 0; i < 4; ++i) o[i] = (a[i] * w0 + bb[i] * w1) * inv;
  *(f4v*)(OUT + row * 64 + d4) = o;
}

extern "C" void kernel_launch(void* const* d_in, const int* in_sizes, int n_in,
                              void* d_out, int out_size, void* d_ws, size_t ws_size,
                              hipStream_t stream) {
  const float* Q = (const float*)d_in[0];
  const float* K = (const float*)d_in[1];
  const float* V = (const float*)d_in[2];
  const float* M = (const float*)d_in[3];
  const float* U = (const float*)d_in[4];
  float* out = (float*)d_out;

  unsigned short* Khf = (unsigned short*)d_ws;              // 8 MB
  unsigned short* Klf = Khf + (size_t)(4u << 20);           // 8 MB
  unsigned short* Vf  = Klf + (size_t)(4u << 20);           // 8 MB
  float* Opart = (float*)(Vf + (size_t)(4u << 20));         // 33.5 MB
  float* ML    = Opart + (size_t)65536 * 128;               // 1 MB
  const size_t need = (size_t)24 * 1024 * 1024 + (size_t)65536 * 132 * 4 + (1u << 20);

  prep_k<<<2048, 256, 0, stream>>>(K, Khf, Klf);
  prep_v<<<2048, 256, 0, stream>>>(V, Vf);
  if (ws_size >= need) {
    attn_fwd<1><<<1024, 256, 0, stream>>>(Q, M, U, Khf, Klf, Vf, out, Opart, ML);
    combine<<<4096, 256, 0, stream>>>(Opart, ML, out);
  } else {
    attn_fwd<0><<<512, 256, 0, stream>>>(Q, M, U, Khf, Klf, Vf, out, Opart, ML);
  }
}